// Round 7
// baseline (218.330 us; speedup 1.0000x reference)
//
#include <hip/hip_runtime.h>
#include <math.h>

#define KNBR 16
#define DIM 64
#define NREL 32
#define WPB 4   // waves per 256-thread block

// ---------------- Kernel 1: one wave per (elem, k) gather unit ----------------
// 65536 waves total -> 16x oversubscription of the 256-CU machine. Slim body
// (~45 VGPR target, below the 64-reg half-occupancy cliff) so 8 waves/EU
// stay resident; 16 batched hop-2 gathers per wave give high MLP.
// Writes per unit: v1 row (hop-1 embedding) and x1 row (v1 + attn1-agg of
// hop-2) to ws[ (elem*16+k) * 2 * 64 ].
__global__ __launch_bounds__(256, 2) void kgnnls_gather(
    const int* __restrict__ u_ids, const int* __restrict__ i_ids,
    const int* __restrict__ adj_entity, const int* __restrict__ adj_relation,
    const float* __restrict__ user_emb, const float* __restrict__ entity_emb,
    const float* __restrict__ relation_emb,
    float* __restrict__ ws, int B)
{
    const int tid  = threadIdx.x;
    const int wave = tid >> 6;
    const int lane = tid & 63;
    int unit = blockIdx.x * WPB + wave;     // B*16 units, grid sized exactly
    if (unit >= B * KNBR) unit = B * KNBR - 1;
    const int elem = unit >> 4;
    const int k    = unit & 15;

    __shared__ float ueb[WPB][DIM];

    const int u  = u_ids[elem];
    const int i0 = i_ids[elem];

    ueb[wave][lane] = user_emb[u * DIM + lane];
    // same-wave DS write->read is pipeline-ordered; no barrier needed

    // s[r] at lane r (r < 33): (1/64) * dot(ue, relation_emb[r])
    float s_val = 0.f;
    if (lane < NREL + 1) {
        const float4* rrow = (const float4*)(relation_emb + lane * DIM);
        const float4* ub   = (const float4*)ueb[wave];
        float acc = 0.f;
        #pragma unroll
        for (int q = 0; q < 16; ++q) {
            float4 r4 = rrow[q];
            float4 u4 = ub[q];   // lane-uniform address -> LDS broadcast
            acc += r4.x*u4.x + r4.y*u4.y + r4.z*u4.z + r4.w*u4.w;
        }
        s_val = acc * (1.0f / DIM);
    }

    const int e1 = adj_entity[i0 * KNBR + k];   // uniform across wave

    // hop-2 neighbor/relation ids at lanes 0..15
    int e2 = 0, r2 = 0;
    if (lane < KNBR) {
        e2 = adj_entity  [e1 * KNBR + lane];
        r2 = adj_relation[e1 * KNBR + lane];
    }

    // softmax over the 16 j's (lanes 0..15)
    float sc = __shfl(s_val, r2);
    float m = sc;
    m = fmaxf(m, __shfl_xor(m, 1));
    m = fmaxf(m, __shfl_xor(m, 2));
    m = fmaxf(m, __shfl_xor(m, 4));
    m = fmaxf(m, __shfl_xor(m, 8));
    float ex = __expf(sc - m);
    float z = ex;
    z += __shfl_xor(z, 1);
    z += __shfl_xor(z, 2);
    z += __shfl_xor(z, 4);
    z += __shfl_xor(z, 8);
    const float attn1 = ex / z;                 // valid at lanes 0..15

    // hop-1 row + 16 batched hop-2 row gathers (lane = d)
    const float v1 = entity_emb[e1 * DIM + lane];
    float v2[KNBR];
    #pragma unroll
    for (int j = 0; j < KNBR; ++j) {
        const int ej = __shfl(e2, j);
        v2[j] = entity_emb[ej * DIM + lane];
    }
    float acc = 0.f;
    #pragma unroll
    for (int j = 0; j < KNBR; ++j)
        acc += __shfl(attn1, j) * v2[j];

    float* wrow = ws + (size_t)unit * (2 * DIM);
    wrow[lane]       = v1;
    wrow[DIM + lane] = v1 + acc * (1.0f / KNBR);   // x1 row
}

// ---------------- Kernel 2: one wave per elem — attn0, MLP tail ----------------
__global__ __launch_bounds__(256, 2) void kgnnls_mlp(
    const int* __restrict__ u_ids, const int* __restrict__ i_ids,
    const int* __restrict__ adj_relation,
    const float* __restrict__ user_emb, const float* __restrict__ entity_emb,
    const float* __restrict__ relation_emb,
    const float* __restrict__ W0, const float* __restrict__ b0,
    const float* __restrict__ W1, const float* __restrict__ b1,
    const float* __restrict__ ws, float* __restrict__ out, int B)
{
    const int tid  = threadIdx.x;
    const int wave = tid >> 6;
    const int lane = tid & 63;
    int b = blockIdx.x * WPB + wave;
    if (b >= B) b = B - 1;

    __shared__ float xbuf[WPB][17][DIM];
    __shared__ float uebuf[WPB][DIM];

    const int u  = u_ids[b];
    const int i0 = i_ids[b];

    const float ue = user_emb[u * DIM + lane];
    uebuf[wave][lane] = ue;
    const float bias0 = b0[lane];

    float s_val = 0.f;
    if (lane < NREL + 1) {
        const float4* rrow = (const float4*)(relation_emb + lane * DIM);
        const float4* ub   = (const float4*)uebuf[wave];
        float acc = 0.f;
        #pragma unroll
        for (int q = 0; q < 16; ++q) {
            float4 r4 = rrow[q];
            float4 u4 = ub[q];
            acc += r4.x*u4.x + r4.y*u4.y + r4.z*u4.z + r4.w*u4.w;
        }
        s_val = acc * (1.0f / DIM);
    }

    int r0k = 0;
    if (lane < KNBR) r0k = adj_relation[i0 * KNBR + lane];

    float sc0 = __shfl(s_val, r0k);
    float m0 = sc0;
    m0 = fmaxf(m0, __shfl_xor(m0, 1));
    m0 = fmaxf(m0, __shfl_xor(m0, 2));
    m0 = fmaxf(m0, __shfl_xor(m0, 4));
    m0 = fmaxf(m0, __shfl_xor(m0, 8));
    float ex0 = __expf(sc0 - m0);
    float z0 = ex0;
    z0 += __shfl_xor(z0, 1);
    z0 += __shfl_xor(z0, 2);
    z0 += __shfl_xor(z0, 4);
    z0 += __shfl_xor(z0, 8);
    const float attn0 = ex0 / z0;   // lanes 0..15

    // stream v1/x1 rows from ws; agg0 from v1, x rows into LDS
    const float* base = ws + (size_t)b * KNBR * 2 * DIM;
    float agg0 = 0.f;
    #pragma unroll
    for (int k = 0; k < KNBR; ++k) {
        const float v1 = base[(k * 2    ) * DIM + lane];
        const float x1 = base[(k * 2 + 1) * DIM + lane];
        agg0 += __shfl(attn0, k) * v1;
        xbuf[wave][1 + k][lane] = x1;
    }
    const float ev0 = entity_emb[i0 * DIM + lane];
    xbuf[wave][0][lane] = ev0 + agg0 * (1.0f / KNBR);
    __syncthreads();

    float h[17];
    #pragma unroll
    for (int r = 0; r < 17; ++r) h[r] = bias0;
    {
        const float4* wrow = (const float4*)(W0 + lane * DIM);
        #pragma unroll
        for (int q = 0; q < 16; ++q) {
            float4 w = wrow[q];
            #pragma unroll
            for (int r = 0; r < 17; ++r) {
                float4 xv = ((const float4*)xbuf[wave][r])[q];
                h[r] += xv.x * w.x + xv.y * w.y + xv.z * w.z + xv.w * w.w;
            }
        }
        #pragma unroll
        for (int r = 0; r < 17; ++r) h[r] = fmaxf(h[r], 0.f);
    }

    float aggL = 0.f;
    #pragma unroll
    for (int k = 0; k < KNBR; ++k)
        aggL += __shfl(attn0, k) * h[1 + k];
    const float xL = h[0] + aggL * (1.0f / KNBR);
    __syncthreads();
    xbuf[wave][0][lane] = xL;
    __syncthreads();

    float acc1 = b1[lane];
    {
        const float4* wrow = (const float4*)(W1 + lane * DIM);
        const float4* xb   = (const float4*)xbuf[wave][0];
        #pragma unroll
        for (int q = 0; q < 16; ++q) {
            float4 w  = wrow[q];
            float4 xv = xb[q];
            acc1 += xv.x * w.x + xv.y * w.y + xv.z * w.z + xv.w * w.w;
        }
    }
    const float item = tanhf(acc1);

    float p = ue * item;
    #pragma unroll
    for (int m = 1; m < 64; m <<= 1) p += __shfl_xor(p, m);
    if (lane == 0) out[b] = 1.0f / (1.0f + __expf(-p));
}

// ---------------- Fallback mono-kernel (R6, used only if ws too small) ----------------
__global__ __launch_bounds__(256, 2) void kgnnls_mono(
    const int* __restrict__ u_ids, const int* __restrict__ i_ids,
    const int* __restrict__ adj_entity, const int* __restrict__ adj_relation,
    const float* __restrict__ user_emb, const float* __restrict__ entity_emb,
    const float* __restrict__ relation_emb,
    const float* __restrict__ W0, const float* __restrict__ b0,
    const float* __restrict__ W1, const float* __restrict__ b1,
    float* __restrict__ out, int B)
{
    const int tid  = threadIdx.x;
    const int wave = tid >> 6;
    const int lane = tid & 63;
    int b = blockIdx.x * WPB + wave;
    if (b >= B) b = B - 1;

    __shared__ float xbuf[WPB][17][DIM];
    __shared__ float uebuf[WPB][DIM];

    const int u  = u_ids[b];
    const int i0 = i_ids[b];

    const float ue = user_emb[u * DIM + lane];
    uebuf[wave][lane] = ue;
    const float bias0 = b0[lane];
    __syncthreads();

    float s_val = 0.f;
    if (lane < NREL + 1) {
        const float4* rrow = (const float4*)(relation_emb + lane * DIM);
        const float4* ub   = (const float4*)uebuf[wave];
        float acc = 0.f;
        #pragma unroll
        for (int q = 0; q < 16; ++q) {
            float4 r4 = rrow[q];
            float4 u4 = ub[q];
            acc += r4.x*u4.x + r4.y*u4.y + r4.z*u4.z + r4.w*u4.w;
        }
        s_val = acc * (1.0f / DIM);
    }

    int e1k = 0, r0k = 0;
    if (lane < KNBR) {
        e1k = adj_entity  [i0 * KNBR + lane];
        r0k = adj_relation[i0 * KNBR + lane];
    }

    float sc0 = __shfl(s_val, r0k);
    float m0 = sc0;
    m0 = fmaxf(m0, __shfl_xor(m0, 1));
    m0 = fmaxf(m0, __shfl_xor(m0, 2));
    m0 = fmaxf(m0, __shfl_xor(m0, 4));
    m0 = fmaxf(m0, __shfl_xor(m0, 8));
    float ex0 = __expf(sc0 - m0);
    float z0 = ex0;
    z0 += __shfl_xor(z0, 1);
    z0 += __shfl_xor(z0, 2);
    z0 += __shfl_xor(z0, 4);
    z0 += __shfl_xor(z0, 8);
    const float attn0 = ex0 / z0;

    const int kk = lane >> 2;
    const int jb = (lane & 3) * 4;
    const int ek = __shfl(e1k, kk);
    const int4 e2i = *(const int4*)(adj_entity  + ek * KNBR + jb);
    const int4 r2i = *(const int4*)(adj_relation + ek * KNBR + jb);
    int e2idx[4] = { e2i.x, e2i.y, e2i.z, e2i.w };

    float sc1[4];
    sc1[0] = __shfl(s_val, r2i.x);
    sc1[1] = __shfl(s_val, r2i.y);
    sc1[2] = __shfl(s_val, r2i.z);
    sc1[3] = __shfl(s_val, r2i.w);

    float m1 = fmaxf(fmaxf(sc1[0], sc1[1]), fmaxf(sc1[2], sc1[3]));
    m1 = fmaxf(m1, __shfl_xor(m1, 1));
    m1 = fmaxf(m1, __shfl_xor(m1, 2));
    float a1[4];
    float z1 = 0.f;
    #pragma unroll
    for (int t = 0; t < 4; ++t) { a1[t] = __expf(sc1[t] - m1); z1 += a1[t]; }
    z1 += __shfl_xor(z1, 1);
    z1 += __shfl_xor(z1, 2);
    const float inv_z1 = 1.0f / z1;
    #pragma unroll
    for (int t = 0; t < 4; ++t) a1[t] *= inv_z1;

    float v1a[KNBR];
    #pragma unroll
    for (int k = 0; k < KNBR; ++k) {
        const int ei = __shfl(e1k, k);
        v1a[k] = entity_emb[ei * DIM + lane];
    }
    const float ev0 = entity_emb[i0 * DIM + lane];

    float agg0 = 0.f;
    for (int k = 0; k < KNBR; ++k) {
        float v2[16];
        #pragma unroll
        for (int j = 0; j < 16; ++j) {
            const int src = 4 * k + (j >> 2);
            const int ei2 = __shfl(e2idx[j & 3], src);
            v2[j] = entity_emb[ei2 * DIM + lane];
        }
        float acc = 0.f;
        #pragma unroll
        for (int j = 0; j < 16; ++j) {
            const int src = 4 * k + (j >> 2);
            acc += __shfl(a1[j & 3], src) * v2[j];
        }
        agg0 += __shfl(attn0, k) * v1a[k];
        xbuf[wave][1 + k][lane] = v1a[k] + acc * (1.0f / KNBR);
    }
    xbuf[wave][0][lane] = ev0 + agg0 * (1.0f / KNBR);
    __syncthreads();

    float h[17];
    #pragma unroll
    for (int r = 0; r < 17; ++r) h[r] = bias0;
    {
        const float4* wrow = (const float4*)(W0 + lane * DIM);
        #pragma unroll
        for (int q = 0; q < 16; ++q) {
            float4 w = wrow[q];
            #pragma unroll
            for (int r = 0; r < 17; ++r) {
                float4 xv = ((const float4*)xbuf[wave][r])[q];
                h[r] += xv.x * w.x + xv.y * w.y + xv.z * w.z + xv.w * w.w;
            }
        }
        #pragma unroll
        for (int r = 0; r < 17; ++r) h[r] = fmaxf(h[r], 0.f);
    }

    float aggL = 0.f;
    #pragma unroll
    for (int k = 0; k < KNBR; ++k)
        aggL += __shfl(attn0, k) * h[1 + k];
    const float xL = h[0] + aggL * (1.0f / KNBR);
    __syncthreads();
    xbuf[wave][0][lane] = xL;
    __syncthreads();

    float acc1 = b1[lane];
    {
        const float4* wrow = (const float4*)(W1 + lane * DIM);
        const float4* xb   = (const float4*)xbuf[wave][0];
        #pragma unroll
        for (int q = 0; q < 16; ++q) {
            float4 w  = wrow[q];
            float4 xv = xb[q];
            acc1 += xv.x * w.x + xv.y * w.y + xv.z * w.z + xv.w * w.w;
        }
    }
    const float item = tanhf(acc1);

    float p = ue * item;
    #pragma unroll
    for (int m = 1; m < 64; m <<= 1) p += __shfl_xor(p, m);
    if (lane == 0) out[b] = 1.0f / (1.0f + __expf(-p));
}

extern "C" void kernel_launch(void* const* d_in, const int* in_sizes, int n_in,
                              void* d_out, int out_size, void* d_ws, size_t ws_size,
                              hipStream_t stream) {
    const int*   u_ids        = (const int*)  d_in[0];
    const int*   i_ids        = (const int*)  d_in[1];
    const int*   adj_entity   = (const int*)  d_in[2];
    const int*   adj_relation = (const int*)  d_in[3];
    const float* user_emb     = (const float*)d_in[4];
    const float* entity_emb   = (const float*)d_in[5];
    const float* relation_emb = (const float*)d_in[6];
    const float* W0           = (const float*)d_in[7];
    const float* b0           = (const float*)d_in[8];
    const float* W1           = (const float*)d_in[9];
    const float* b1           = (const float*)d_in[10];
    float* out = (float*)d_out;

    const int B = in_sizes[0];
    const size_t ws_needed = (size_t)B * KNBR * 2 * DIM * sizeof(float);  // 33.5 MB @ B=4096

    if (ws_size >= ws_needed) {
        const int grid1 = (B * KNBR + WPB - 1) / WPB;   // 16384 blocks
        hipLaunchKernelGGL(kgnnls_gather, dim3(grid1), dim3(64 * WPB), 0, stream,
            u_ids, i_ids, adj_entity, adj_relation, user_emb, entity_emb,
            relation_emb, (float*)d_ws, B);
        const int grid2 = (B + WPB - 1) / WPB;
        hipLaunchKernelGGL(kgnnls_mlp, dim3(grid2), dim3(64 * WPB), 0, stream,
            u_ids, i_ids, adj_relation, user_emb, entity_emb, relation_emb,
            W0, b0, W1, b1, (const float*)d_ws, out, B);
    } else {
        const int grid = (B + WPB - 1) / WPB;
        hipLaunchKernelGGL(kgnnls_mono, dim3(grid), dim3(64 * WPB), 0, stream,
            u_ids, i_ids, adj_entity, adj_relation, user_emb, entity_emb,
            relation_emb, W0, b0, W1, b1, out, B);
    }
}

// Round 8
// 157.523 us; speedup vs baseline: 1.3860x; 1.3860x over previous
//
#include <hip/hip_runtime.h>
#include <math.h>

#define KNBR 16
#define DIM 64
#define NREL 32
#define WPB 4   // batch elements (one wave each) per 256-thread block

// v_readlane_b32: cross-lane read -> SGPR, no LDS-pipe traffic (vs __shfl's
// ds_bpermute, ~6cyc on the shared LDS pipe). Lane index may be imm or SGPR.
__device__ __forceinline__ int irl(int v, int l) {
    return __builtin_amdgcn_readlane(v, l);
}
__device__ __forceinline__ float frl(float v, int l) {
    return __int_as_float(__builtin_amdgcn_readlane(__float_as_int(v), l));
}

// launch_bounds(256,2): compiler VGPR budget 128 (fitted: budget=256/waves_per_EU).
// Grid = 4096 waves -> 16 waves/CU cap; HW allows 16/CU up to 127 VGPRs, so the
// 128 budget costs nothing. R8 change vs R6: all inner-loop __shfl -> readlane
// (SALU), making gather indices SGPRs -> scalar-base loads, deep vmcnt batching.
__global__ __launch_bounds__(256, 2) void kgnnls_kernel(
    const int* __restrict__ u_ids, const int* __restrict__ i_ids,
    const int* __restrict__ adj_entity, const int* __restrict__ adj_relation,
    const float* __restrict__ user_emb, const float* __restrict__ entity_emb,
    const float* __restrict__ relation_emb,
    const float* __restrict__ W0, const float* __restrict__ b0,
    const float* __restrict__ W1, const float* __restrict__ b1,
    float* __restrict__ out, int B)
{
    const int tid  = threadIdx.x;
    const int wave = tid >> 6;
    const int lane = tid & 63;          // dual role: dim index d / output index e
    int b = blockIdx.x * WPB + wave;
    if (b >= B) b = B - 1;              // duplicate work, benign duplicate write

    __shared__ float xbuf[WPB][17][DIM];
    __shared__ float uebuf[WPB][DIM];

    const int u  = u_ids[b];
    const int i0 = i_ids[b];

    const float ue = user_emb[u * DIM + lane];
    uebuf[wave][lane] = ue;
    const float bias0 = b0[lane];

    __syncthreads();

    // s[r] at lane r (r < 33): s = (1/64) * dot(ue, relation_emb[r])
    float s_val = 0.f;
    if (lane < NREL + 1) {
        const float4* rrow = (const float4*)(relation_emb + lane * DIM);
        const float4* ub   = (const float4*)uebuf[wave];
        float acc = 0.f;
        #pragma unroll
        for (int q = 0; q < 16; ++q) {
            float4 r4 = rrow[q];
            float4 u4 = ub[q];   // same address across lanes -> LDS broadcast
            acc += r4.x*u4.x + r4.y*u4.y + r4.z*u4.z + r4.w*u4.w;
        }
        s_val = acc * (1.0f / DIM);
    }

    // hop-0 neighbor/relation indices at lanes 0..15
    int e1k = 0, r0k = 0;
    if (lane < KNBR) {
        e1k = adj_entity  [i0 * KNBR + lane];
        r0k = adj_relation[i0 * KNBR + lane];
    }

    // softmax over k (16) for hop-0 scores, valid at lanes 0..15
    float sc0 = __shfl(s_val, r0k);      // data-dependent lane -> keep bpermute
    float m0 = sc0;
    m0 = fmaxf(m0, __shfl_xor(m0, 1));
    m0 = fmaxf(m0, __shfl_xor(m0, 2));
    m0 = fmaxf(m0, __shfl_xor(m0, 4));
    m0 = fmaxf(m0, __shfl_xor(m0, 8));
    float ex0 = __expf(sc0 - m0);
    float z0 = ex0;
    z0 += __shfl_xor(z0, 1);
    z0 += __shfl_xor(z0, 2);
    z0 += __shfl_xor(z0, 4);
    z0 += __shfl_xor(z0, 8);
    const float attn0 = ex0 / z0;     // lanes 0..15 hold attn0[k]

    // hop-1: lane handles k = lane>>2, j in [4*(lane&3), +4)
    const int kk = lane >> 2;
    const int jb = (lane & 3) * 4;
    const int ek = irl(e1k, kk);      // uniform per 4-lane group? no: kk varies,
                                      // but irl needs uniform idx -> use shfl here
    // NOTE: kk is per-lane, readlane would be wrong; revert to bpermute for this one.
    const int ek_v = __shfl(e1k, kk);
    (void)ek;
    const int4 e2i = *(const int4*)(adj_entity  + ek_v * KNBR + jb);
    const int4 r2i = *(const int4*)(adj_relation + ek_v * KNBR + jb);
    int e2idx[4] = { e2i.x, e2i.y, e2i.z, e2i.w };

    float sc1[4];
    sc1[0] = __shfl(s_val, r2i.x);    // data-dependent lanes -> bpermute
    sc1[1] = __shfl(s_val, r2i.y);
    sc1[2] = __shfl(s_val, r2i.z);
    sc1[3] = __shfl(s_val, r2i.w);

    // softmax over the 16 j's: intra-lane over 4 + xor over lanes {1,2}
    float m1 = fmaxf(fmaxf(sc1[0], sc1[1]), fmaxf(sc1[2], sc1[3]));
    m1 = fmaxf(m1, __shfl_xor(m1, 1));
    m1 = fmaxf(m1, __shfl_xor(m1, 2));
    float a1[4];
    float z1 = 0.f;
    #pragma unroll
    for (int t = 0; t < 4; ++t) { a1[t] = __expf(sc1[t] - m1); z1 += a1[t]; }
    z1 += __shfl_xor(z1, 1);
    z1 += __shfl_xor(z1, 2);
    const float inv_z1 = 1.0f / z1;
    #pragma unroll
    for (int t = 0; t < 4; ++t) a1[t] *= inv_z1;

    // ---- Gather phase: all indices via readlane -> SGPR -> scalar-base loads ----
    float v1a[KNBR];
    #pragma unroll
    for (int k = 0; k < KNBR; ++k) {
        const int ei = irl(e1k, k);                    // imm lane
        v1a[k] = entity_emb[(size_t)ei * DIM + lane];  // SGPR base + lane*4
    }
    const float ev0 = entity_emb[(size_t)i0 * DIM + lane];

    float agg0 = 0.f;
    for (int k = 0; k < KNBR; ++k) {                   // k: uniform SGPR loop var
        float v2[16];
        #pragma unroll
        for (int j = 0; j < 16; ++j) {
            const int src = 4 * k + (j >> 2);          // uniform (SGPR) lane idx
            const int ei2 = irl(e2idx[j & 3], src);
            v2[j] = entity_emb[(size_t)ei2 * DIM + lane];
        }
        float acc = 0.f;
        #pragma unroll
        for (int j = 0; j < 16; ++j) {
            const int src = 4 * k + (j >> 2);
            acc += frl(a1[j & 3], src) * v2[j];        // SGPR weight operand
        }
        agg0 += frl(attn0, k) * v1a[k];
        xbuf[wave][1 + k][lane] = v1a[k] + acc * (1.0f / KNBR);
    }
    xbuf[wave][0][lane] = ev0 + agg0 * (1.0f / KNBR);
    __syncthreads();

    // Layer-0 matmul: h[r][e] = relu( sum_d x[r][d] * W0[e][d] + b0[e] ), 17 rows
    float h[17];
    {
        #pragma unroll
        for (int r = 0; r < 17; ++r) h[r] = bias0;
        const float4* wrow = (const float4*)(W0 + lane * DIM);
        #pragma unroll
        for (int q = 0; q < 16; ++q) {
            float4 w = wrow[q];   // L1-resident
            #pragma unroll
            for (int r = 0; r < 17; ++r) {
                float4 xv = ((const float4*)xbuf[wave][r])[q];  // broadcast read
                h[r] += xv.x * w.x + xv.y * w.y + xv.z * w.z + xv.w * w.w;
            }
        }
        #pragma unroll
        for (int r = 0; r < 17; ++r) h[r] = fmaxf(h[r], 0.f);
    }

    // Layer-1: agg over h1 with the SAME attn0, then tanh((h0+agg) @ W1^T + b1)
    float aggL = 0.f;
    #pragma unroll
    for (int k = 0; k < KNBR; ++k)
        aggL += frl(attn0, k) * h[1 + k];              // imm-lane readlane
    const float xL = h[0] + aggL * (1.0f / KNBR);
    __syncthreads();
    xbuf[wave][0][lane] = xL;
    __syncthreads();

    float acc1 = b1[lane];
    {
        const float4* wrow = (const float4*)(W1 + lane * DIM);
        const float4* xb   = (const float4*)xbuf[wave][0];
        #pragma unroll
        for (int q = 0; q < 16; ++q) {
            float4 w  = wrow[q];
            float4 xv = xb[q];
            acc1 += xv.x * w.x + xv.y * w.y + xv.z * w.z + xv.w * w.w;
        }
    }
    const float item = tanhf(acc1);

    // score = sigmoid( sum_d ue[d] * item[d] )
    float p = ue * item;
    #pragma unroll
    for (int m = 1; m < 64; m <<= 1) p += __shfl_xor(p, m);
    if (lane == 0) out[b] = 1.0f / (1.0f + __expf(-p));
}

extern "C" void kernel_launch(void* const* d_in, const int* in_sizes, int n_in,
                              void* d_out, int out_size, void* d_ws, size_t ws_size,
                              hipStream_t stream) {
    const int*   u_ids        = (const int*)  d_in[0];
    const int*   i_ids        = (const int*)  d_in[1];
    const int*   adj_entity   = (const int*)  d_in[2];
    const int*   adj_relation = (const int*)  d_in[3];
    const float* user_emb     = (const float*)d_in[4];
    const float* entity_emb   = (const float*)d_in[5];
    const float* relation_emb = (const float*)d_in[6];
    const float* W0           = (const float*)d_in[7];
    const float* b0           = (const float*)d_in[8];
    const float* W1           = (const float*)d_in[9];
    const float* b1           = (const float*)d_in[10];
    float* out = (float*)d_out;

    const int B = in_sizes[0];
    const int grid = (B + WPB - 1) / WPB;
    hipLaunchKernelGGL(kgnnls_kernel, dim3(grid), dim3(64 * WPB), 0, stream,
        u_ids, i_ids, adj_entity, adj_relation, user_emb, entity_emb,
        relation_emb, W0, b0, W1, b1, out, B);
}

// Round 9
// 157.223 us; speedup vs baseline: 1.3887x; 1.0019x over previous
//
#include <hip/hip_runtime.h>
#include <math.h>

#define KNBR 16
#define DIM 64
#define NREL 32
#define WPB 4   // batch elements (one wave each) per 256-thread block

// v_readlane_b32: cross-lane read -> SGPR, no LDS-pipe traffic. Lane index
// must be imm or SGPR (uniform) -- all uses below are unrolled consts or
// uniform loop vars.
__device__ __forceinline__ int irl(int v, int l) {
    return __builtin_amdgcn_readlane(v, l);
}
__device__ __forceinline__ float frl(float v, int l) {
    return __int_as_float(__builtin_amdgcn_readlane(__float_as_int(v), l));
}

// launch_bounds(256,2): compiler VGPR budget 128 (fitted: budget=256/waves_per_EU).
// Grid = 4096 waves -> 16 waves/CU cap; HW allows 16/CU up to 128 VGPRs, so a
// ~112-reg body costs nothing. R9 vs R8: gather loop batches 4 k's (v2[64],
// 64 loads in flight) to raise per-CU outstanding loads (Little's law said
// ~12-18 outstanding @ 2.17 TB/s -- the limiter).
__global__ __launch_bounds__(256, 2) void kgnnls_kernel(
    const int* __restrict__ u_ids, const int* __restrict__ i_ids,
    const int* __restrict__ adj_entity, const int* __restrict__ adj_relation,
    const float* __restrict__ user_emb, const float* __restrict__ entity_emb,
    const float* __restrict__ relation_emb,
    const float* __restrict__ W0, const float* __restrict__ b0,
    const float* __restrict__ W1, const float* __restrict__ b1,
    float* __restrict__ out, int B)
{
    const int tid  = threadIdx.x;
    const int wave = tid >> 6;
    const int lane = tid & 63;          // dual role: dim index d / output index e
    int b = blockIdx.x * WPB + wave;
    if (b >= B) b = B - 1;              // duplicate work, benign duplicate write

    __shared__ float xbuf[WPB][17][DIM];
    __shared__ float uebuf[WPB][DIM];

    const int u  = u_ids[b];
    const int i0 = i_ids[b];

    const float ue = user_emb[u * DIM + lane];
    uebuf[wave][lane] = ue;
    const float bias0 = b0[lane];

    __syncthreads();

    // s[r] at lane r (r < 33): s = (1/64) * dot(ue, relation_emb[r])
    float s_val = 0.f;
    if (lane < NREL + 1) {
        const float4* rrow = (const float4*)(relation_emb + lane * DIM);
        const float4* ub   = (const float4*)uebuf[wave];
        float acc = 0.f;
        #pragma unroll
        for (int q = 0; q < 16; ++q) {
            float4 r4 = rrow[q];
            float4 u4 = ub[q];   // same address across lanes -> LDS broadcast
            acc += r4.x*u4.x + r4.y*u4.y + r4.z*u4.z + r4.w*u4.w;
        }
        s_val = acc * (1.0f / DIM);
    }

    // hop-0 neighbor/relation indices at lanes 0..15
    int e1k = 0, r0k = 0;
    if (lane < KNBR) {
        e1k = adj_entity  [i0 * KNBR + lane];
        r0k = adj_relation[i0 * KNBR + lane];
    }

    // softmax over k (16) for hop-0 scores, valid at lanes 0..15
    float sc0 = __shfl(s_val, r0k);      // data-dependent lane -> bpermute
    float m0 = sc0;
    m0 = fmaxf(m0, __shfl_xor(m0, 1));
    m0 = fmaxf(m0, __shfl_xor(m0, 2));
    m0 = fmaxf(m0, __shfl_xor(m0, 4));
    m0 = fmaxf(m0, __shfl_xor(m0, 8));
    float ex0 = __expf(sc0 - m0);
    float z0 = ex0;
    z0 += __shfl_xor(z0, 1);
    z0 += __shfl_xor(z0, 2);
    z0 += __shfl_xor(z0, 4);
    z0 += __shfl_xor(z0, 8);
    const float attn0 = ex0 / z0;     // lanes 0..15 hold attn0[k]

    // hop-1: lane handles k = lane>>2, j in [4*(lane&3), +4)
    const int kk = lane >> 2;
    const int jb = (lane & 3) * 4;
    const int ek = __shfl(e1k, kk);   // per-lane index -> bpermute
    const int4 e2i = *(const int4*)(adj_entity  + ek * KNBR + jb);
    const int4 r2i = *(const int4*)(adj_relation + ek * KNBR + jb);
    int e2idx[4] = { e2i.x, e2i.y, e2i.z, e2i.w };

    float sc1[4];
    sc1[0] = __shfl(s_val, r2i.x);    // data-dependent lanes -> bpermute
    sc1[1] = __shfl(s_val, r2i.y);
    sc1[2] = __shfl(s_val, r2i.z);
    sc1[3] = __shfl(s_val, r2i.w);

    // softmax over the 16 j's: intra-lane over 4 + xor over lanes {1,2}
    float m1 = fmaxf(fmaxf(sc1[0], sc1[1]), fmaxf(sc1[2], sc1[3]));
    m1 = fmaxf(m1, __shfl_xor(m1, 1));
    m1 = fmaxf(m1, __shfl_xor(m1, 2));
    float a1[4];
    float z1 = 0.f;
    #pragma unroll
    for (int t = 0; t < 4; ++t) { a1[t] = __expf(sc1[t] - m1); z1 += a1[t]; }
    z1 += __shfl_xor(z1, 1);
    z1 += __shfl_xor(z1, 2);
    const float inv_z1 = 1.0f / z1;
    #pragma unroll
    for (int t = 0; t < 4; ++t) a1[t] *= inv_z1;

    // ---- Gather phase: indices via readlane (SGPR base), 64 loads in flight ----
    float v1a[KNBR];
    #pragma unroll
    for (int k = 0; k < KNBR; ++k) {
        const int ei = irl(e1k, k);                    // imm lane
        v1a[k] = entity_emb[(size_t)ei * DIM + lane];  // SGPR base + lane*4
    }
    const float ev0 = entity_emb[(size_t)i0 * DIM + lane];

    float agg0 = 0.f;
    #pragma unroll 1   // keep batches sequential: v2[64] stays 64 regs, no blowup
    for (int kb = 0; kb < 4; ++kb) {
        float v2[64];
        // issue all 64 gathers for k = 4*kb .. 4*kb+3 before consuming any
        #pragma unroll
        for (int t = 0; t < 4; ++t) {
            const int k = kb * 4 + t;                  // uniform (SGPR)
            #pragma unroll
            for (int j = 0; j < 16; ++j) {
                const int src = 4 * k + (j >> 2);      // uniform lane idx
                const int ei2 = irl(e2idx[j & 3], src);
                v2[t * 16 + j] = entity_emb[(size_t)ei2 * DIM + lane];
            }
        }
        // consume in issue order (incremental vmcnt waits)
        #pragma unroll
        for (int t = 0; t < 4; ++t) {
            const int k = kb * 4 + t;
            float acc = 0.f;
            #pragma unroll
            for (int j = 0; j < 16; ++j) {
                const int src = 4 * k + (j >> 2);
                acc += frl(a1[j & 3], src) * v2[t * 16 + j];
            }
            agg0 += frl(attn0, k) * v1a[k];
            xbuf[wave][1 + k][lane] = v1a[k] + acc * (1.0f / KNBR);
        }
    }
    xbuf[wave][0][lane] = ev0 + agg0 * (1.0f / KNBR);
    __syncthreads();

    // Layer-0 matmul: h[r][e] = relu( sum_d x[r][d] * W0[e][d] + b0[e] ), 17 rows
    float h[17];
    {
        #pragma unroll
        for (int r = 0; r < 17; ++r) h[r] = bias0;
        const float4* wrow = (const float4*)(W0 + lane * DIM);
        #pragma unroll
        for (int q = 0; q < 16; ++q) {
            float4 w = wrow[q];   // L1-resident
            #pragma unroll
            for (int r = 0; r < 17; ++r) {
                float4 xv = ((const float4*)xbuf[wave][r])[q];  // broadcast read
                h[r] += xv.x * w.x + xv.y * w.y + xv.z * w.z + xv.w * w.w;
            }
        }
        #pragma unroll
        for (int r = 0; r < 17; ++r) h[r] = fmaxf(h[r], 0.f);
    }

    // Layer-1: agg over h1 with the SAME attn0, then tanh((h0+agg) @ W1^T + b1)
    float aggL = 0.f;
    #pragma unroll
    for (int k = 0; k < KNBR; ++k)
        aggL += frl(attn0, k) * h[1 + k];              // imm-lane readlane
    const float xL = h[0] + aggL * (1.0f / KNBR);
    __syncthreads();
    xbuf[wave][0][lane] = xL;
    __syncthreads();

    float acc1 = b1[lane];
    {
        const float4* wrow = (const float4*)(W1 + lane * DIM);
        const float4* xb   = (const float4*)xbuf[wave][0];
        #pragma unroll
        for (int q = 0; q < 16; ++q) {
            float4 w  = wrow[q];
            float4 xv = xb[q];
            acc1 += xv.x * w.x + xv.y * w.y + xv.z * w.z + xv.w * w.w;
        }
    }
    const float item = tanhf(acc1);

    // score = sigmoid( sum_d ue[d] * item[d] )
    float p = ue * item;
    #pragma unroll
    for (int m = 1; m < 64; m <<= 1) p += __shfl_xor(p, m);
    if (lane == 0) out[b] = 1.0f / (1.0f + __expf(-p));
}

extern "C" void kernel_launch(void* const* d_in, const int* in_sizes, int n_in,
                              void* d_out, int out_size, void* d_ws, size_t ws_size,
                              hipStream_t stream) {
    const int*   u_ids        = (const int*)  d_in[0];
    const int*   i_ids        = (const int*)  d_in[1];
    const int*   adj_entity   = (const int*)  d_in[2];
    const int*   adj_relation = (const int*)  d_in[3];
    const float* user_emb     = (const float*)d_in[4];
    const float* entity_emb   = (const float*)d_in[5];
    const float* relation_emb = (const float*)d_in[6];
    const float* W0           = (const float*)d_in[7];
    const float* b0           = (const float*)d_in[8];
    const float* W1           = (const float*)d_in[9];
    const float* b1           = (const float*)d_in[10];
    float* out = (float*)d_out;

    const int B = in_sizes[0];
    const int grid = (B + WPB - 1) / WPB;
    hipLaunchKernelGGL(kgnnls_kernel, dim3(grid), dim3(64 * WPB), 0, stream,
        u_ids, i_ids, adj_entity, adj_relation, user_emb, entity_emb,
        relation_emb, W0, b0, W1, b1, out, B);
}